// Round 7
// baseline (230.808 us; speedup 1.0000x reference)
//
#include <hip/hip_runtime.h>
#include <stdint.h>

#define GD    34
#define RS    39          // row stride; 39%32=7 -> sparse lane aliasing only
#define NPIX  1156
#define NT    256
#define NB    1024
#define TPR   7           // 5-pixel strips per row (7*5=35 >= 34)
#define TUSED 238         // 34 rows * 7 strips
#define FS    57          // food-halo row stride (init-only, aliases c0b/cb1/cb2)
#define ONEB  0x3f800000u // bits of 1.0f

// pool layout (float offsets)
#define O_C0B 0           // ch0, 1-halo 36x39
#define O_CB1 1404        // ch1, 1-halo
#define O_CB2 2808        // ch2, 1-halo
#define O_X0  4212        // x_new ch0 pre-mask/clip, 1-halo
#define O_X1  5616        // x_new ch1 staging, flat [1156]
#define O_X2  6772        // x_new ch2 staging, flat [1156]
#define O_X3  7928        // x_new ch3 staging, flat [1156]; hist[1088] aliases
#define POOLN 9084        // 36.3 KB -> 4 blocks/CU

// bin -> conflict-free LDS index: groups of 16 bins at stride 17.
#define HIDX(bb) ((bb) + ((bb) >> 4))

// wave0 scans the 1024-bin histogram, finds the bin containing rank KK,
// writes sel_bin/sel_rem, zeroes the histogram behind itself.
#define SCAN_PASS(KK) do {                                                         \
    if (wid == 0) {                                                                \
      const int hb = 17 * lane;                                                    \
      int c16[16]; int csum = 0;                                                   \
      _Pragma("unroll")                                                            \
      for (int j = 0; j < 16; ++j) { c16[j] = hist[hb+j]; hist[hb+j] = 0; csum += c16[j]; } \
      int inc2 = csum;                                                             \
      _Pragma("unroll")                                                            \
      for (int off2 = 1; off2 < 64; off2 <<= 1) { int vv = __shfl_up(inc2, off2); if (lane >= off2) inc2 += vv; } \
      const int excl = inc2 - csum;                                                \
      if ((KK) >= excl && (KK) < inc2) {                                           \
        int rem = (KK) - excl; int cum = 0;                                        \
        _Pragma("unroll")                                                          \
        for (int j = 0; j < 16; ++j) {                                             \
          if (rem >= cum && rem < cum + c16[j]) { sel_bin = (lane << 4) + j; sel_rem = rem - cum; } \
          cum += c16[j];                                                           \
        }                                                                          \
      }                                                                            \
    }                                                                              \
  } while (0)

__global__ __launch_bounds__(NT) __attribute__((amdgpu_waves_per_eu(4, 4)))
void ca_kernel(const float* __restrict__ cell_in,   // [B,4,34,34]
               const float* __restrict__ food_in,   // [B,34,34]
               const float* __restrict__ fc1_w,     // [64,12] (wave-uniform scalar reads)
               const float* __restrict__ fc1_b,     // [64]
               const float* __restrict__ fc2_w,     // [4,64]
               const float* __restrict__ fc2_b,     // [4]
               const float* __restrict__ sk_g,      // [19,19]
               const int*   __restrict__ steps_p,
               float* __restrict__ out)             // [cell | food | tpv | lc]
{
  __shared__ float pool[POOLN];
  __shared__ unsigned long long avb[2][38]; // alive bits: word=row+2, bit=col+2 (halo=0)
  __shared__ int   icl[2][4];
  __shared__ int   inzaz[4];
  __shared__ int   ion[4];
  __shared__ int   sel_bin, sel_rem;
  __shared__ float fsum[4];
  __shared__ int   lcnt[4];

  float* c0b  = pool + O_C0B;
  float* cb1  = pool + O_CB1;
  float* cb2  = pool + O_CB2;
  float* x0p  = pool + O_X0;
  float* x1p  = pool + O_X1;
  float* x2p  = pool + O_X2;
  float* x3p  = pool + O_X3;
  int*   hist = (int*)(pool + O_X3);    // aliases x3p: radix-only, zeroed on entry
  float* foodc = pool;                  // init-only 52x57 food halo (max idx 2959 < 4212)

  const int tid  = threadIdx.x;
  const int b    = blockIdx.x;
  const int lane = tid & 63;
  const int wid  = tid >> 6;
  const int nsteps = steps_p[0];

  const bool tval = (tid < TUSED);
  const int  trow = tval ? (tid / TPR) : 0;
  const int  c0   = tval ? ((tid % TPR) * 5) : 0;
  const int  nval = tval ? ((c0 <= 29) ? 5 : 4) : 0;   // strip 6 covers cols 30..33
  const int  pb1  = (trow+1)*RS + c0 + 1;              // own pixel in 1-halo bufs
  const int  p0   = trow*GD + c0;                      // flat pixel base

  // ---------------- init ----------------
  for (int idx = tid; idx < POOLN; idx += NT) pool[idx] = 0.f;
  for (int idx = tid; idx < 76;    idx += NT) ((unsigned long long*)avb)[idx] = 0ull;
  __syncthreads();

  // food into 9-halo conv scratch (aliases c0b/cb1/cb2 region; re-zeroed after conv)
#pragma unroll
  for (int j = 0; j < 5; ++j)
    if (j < nval) foodc[(trow+9)*FS + (c0+j+9)] = food_in[(size_t)b*NPIX + p0 + j];
  __syncthreads();

  // scent: 19x19 gaussian conv, once. Row-register reuse; per-pixel accumulation order
  // identical to naive dr-outer/dc-inner -> bit-exact.
  float scent[5] = {0.f, 0.f, 0.f, 0.f, 0.f};
  for (int dr = 0; dr < 19; ++dr) {
    const float* frow = foodc + (trow+dr)*FS + c0;
    float f[23];
#pragma unroll
    for (int q = 0; q < 23; ++q) f[q] = frow[q];
    const float* krow = sk_g + dr*19;
#pragma unroll
    for (int dc = 0; dc < 19; ++dc) {
      const float kv = krow[dc];
      scent[0] = fmaf(f[dc+0], kv, scent[0]);
      scent[1] = fmaf(f[dc+1], kv, scent[1]);
      scent[2] = fmaf(f[dc+2], kv, scent[2]);
      scent[3] = fmaf(f[dc+3], kv, scent[3]);
      scent[4] = fmaf(f[dc+4], kv, scent[4]);
    }
  }
  __syncthreads();
  for (int idx = tid; idx < O_X0; idx += NT) pool[idx] = 0.f;  // restore c0b/cb1/cb2 zeros
  __syncthreads();

  // load state; publish initial alive bits + living count
  float v3k[5];
  unsigned long long avm0 = 0ull;
  int cnt0 = 0;
#pragma unroll
  for (int j = 0; j < 5; ++j) {
    v3k[j] = 0.f;
    if (j < nval) {
      const float* gi = cell_in + (size_t)b*4*NPIX + p0 + j;
      float v0 = gi[0], v1 = gi[NPIX], v2 = gi[2*NPIX], v3 = gi[3*NPIX];
      c0b[pb1+j] = v0; cb1[pb1+j] = v1; cb2[pb1+j] = v2;
      v3k[j] = v3;
      cnt0 += (v0 > 0.8f) ? 1 : 0;
      if (v0 > 0.1f) avm0 |= (1ull << j);
      x0p[pb1+j] = scent[j];           // scent staging for step-invariant ch3 sobels
    }
  }
  if (avm0) atomicOr(&avb[0][trow+2], avm0 << (c0+2));
#pragma unroll
  for (int off = 32; off; off >>= 1) cnt0 += __shfl_down(cnt0, off);
  if (lane == 0) icl[0][wid] = cnt0;
  __syncthreads();
  float sxs[5], sys[5];
#pragma unroll
  for (int j = 0; j < 5; ++j) {
    const int bb = (j < nval) ? (pb1 + j) : pb1;
    float t00=x0p[bb-RS-1], t01=x0p[bb-RS], t02=x0p[bb-RS+1];
    float t10=x0p[bb-1],                    t12=x0p[bb+1];
    float t20=x0p[bb+RS-1], t21=x0p[bb+RS], t22=x0p[bb+RS+1];
    sxs[j] = ((t02 - t00) + 2.f*(t12 - t10) + (t22 - t20)) * 0.125f;
    sys[j] = ((t20 - t00) + 2.f*(t21 - t01) + (t22 - t02)) * 0.125f;
  }
  // x0p stale entries are safe: C reads only dilate1(pm) positions == am, all MLP-fresh

  const float b2r0 = fc2_b[0], b2r1 = fc2_b[1], b2r2 = fc2_b[2], b2r3 = fc2_b[3];

  // ---------------- steps ----------------
  for (int s = 0; s < nsteps; ++s) {
    __syncthreads();                     // (1) prev writeback + avb visible
    // --- P1 via alive-bitmask: pm = maxpool3>0.1 == OR_3x3(av), am = maxpool5>0.1 ---
    const unsigned long long* av = avb[s&1];
    const unsigned long long q0 = av[trow],   q1 = av[trow+1], q2 = av[trow+2],
                             q3 = av[trow+3], q4 = av[trow+4];
    const unsigned long long or3 = q1 | q2 | q3;
    const unsigned long long or5 = or3 | q0 | q4;
    unsigned pm = 0, am = 0;
#pragma unroll
    for (int j = 0; j < 5; ++j) {
      if (j < nval) {
        if ((or3 >> (c0+j+1)) & 7ull)  pm |= (1u << j);
        if ((or5 >> (c0+j))   & 31ull) am |= (1u << j);
      }
    }
    // --- MLP: wave-local compaction. Active pairs (lane,j) enumerated by (j, lane);
    //     each compute lane reads all inputs from LDS (identical values -> fp32 bit-exact),
    //     scent/sxs/sys shuffled from the owner lane's registers. ---
    {
      const unsigned long long mk0 = __ballot((am >> 0) & 1u);
      const unsigned long long mk1 = __ballot((am >> 1) & 1u);
      const unsigned long long mk2 = __ballot((am >> 2) & 1u);
      const unsigned long long mk3 = __ballot((am >> 3) & 1u);
      const unsigned long long mk4 = __ballot((am >> 4) & 1u);
      const int P0 = __popcll(mk0);
      const int P1 = P0 + __popcll(mk1);
      const int P2 = P1 + __popcll(mk2);
      const int P3 = P2 + __popcll(mk3);
      const int Ntot = P3 + __popcll(mk4);
      const int rounds = (Ntot + 63) >> 6;
      for (int r = 0; r < rounds; ++r) {
        const int i = (r << 6) + lane;
        if (i < Ntot) {
          // select (jj, rank t) then the t-th set bit of mask jj
          const int jj = (i >= P0) + (i >= P1) + (i >= P2) + (i >= P3);
          int base = 0;
          base = (jj >= 1) ? P0 : base; base = (jj >= 2) ? P1 : base;
          base = (jj >= 3) ? P2 : base; base = (jj >= 4) ? P3 : base;
          int tt = i - base;
          unsigned long long mm = mk0;
          mm = (jj == 1) ? mk1 : mm; mm = (jj == 2) ? mk2 : mm;
          mm = (jj == 3) ? mk3 : mm; mm = (jj == 4) ? mk4 : mm;
          int pos = 0;
#pragma unroll
          for (int bb2 = 32; bb2 >= 1; bb2 >>= 1) {
            int cw = __popcll(mm & (((1ull << bb2) - 1ull) << pos));
            if (tt >= cw) { tt -= cw; pos += bb2; }
          }
          // owner thread -> pixel coords (magic /7 valid for ts<=255)
          const int ts  = (wid << 6) + pos;
          const int trw = (ts * 9363) >> 16;
          const int col = (ts - trw * 7) * 5 + jj;
          const int p   = trw * GD + col;
          const int h0  = (trw + 1) * RS + col + 1;
          // scent/sxs/sys from the owner lane (bit-exact register values)
          float s0v = __shfl(scent[0], pos), s1v = __shfl(scent[1], pos),
                s2v = __shfl(scent[2], pos), s3v = __shfl(scent[3], pos),
                s4v = __shfl(scent[4], pos);
          float a0v = __shfl(sxs[0], pos), a1v = __shfl(sxs[1], pos),
                a2v = __shfl(sxs[2], pos), a3v = __shfl(sxs[3], pos),
                a4v = __shfl(sxs[4], pos);
          float b0v = __shfl(sys[0], pos), b1v = __shfl(sys[1], pos),
                b2v = __shfl(sys[2], pos), b3v = __shfl(sys[3], pos),
                b4v = __shfl(sys[4], pos);
          const float y3  = (jj==0)?s0v:(jj==1)?s1v:(jj==2)?s2v:(jj==3)?s3v:s4v;
          const float y7  = (jj==0)?a0v:(jj==1)?a1v:(jj==2)?a2v:(jj==3)?a3v:a4v;
          const float y11 = (jj==0)?b0v:(jj==1)?b1v:(jj==2)?b2v:(jj==3)?b3v:b4v;
          float y0, y4, y8, y1, y5, y9, y2, y6, y10;
          {
            const float* cb = c0b;
            float t00=cb[h0-RS-1], t01=cb[h0-RS], t02=cb[h0-RS+1];
            float t10=cb[h0-1],    t11=cb[h0],    t12=cb[h0+1];
            float t20=cb[h0+RS-1], t21=cb[h0+RS], t22=cb[h0+RS+1];
            y0 = t11;
            y4 = ((t02 - t00) + 2.f*(t12 - t10) + (t22 - t20)) * 0.125f;
            y8 = ((t20 - t00) + 2.f*(t21 - t01) + (t22 - t02)) * 0.125f;
          }
          {
            const float* cb = cb1;
            float t00=cb[h0-RS-1], t01=cb[h0-RS], t02=cb[h0-RS+1];
            float t10=cb[h0-1],    t11=cb[h0],    t12=cb[h0+1];
            float t20=cb[h0+RS-1], t21=cb[h0+RS], t22=cb[h0+RS+1];
            y1 = t11;
            y5 = ((t02 - t00) + 2.f*(t12 - t10) + (t22 - t20)) * 0.125f;
            y9 = ((t20 - t00) + 2.f*(t21 - t01) + (t22 - t02)) * 0.125f;
          }
          {
            const float* cb = cb2;
            float t00=cb[h0-RS-1], t01=cb[h0-RS], t02=cb[h0-RS+1];
            float t10=cb[h0-1],    t11=cb[h0],    t12=cb[h0+1];
            float t20=cb[h0+RS-1], t21=cb[h0+RS], t22=cb[h0+RS+1];
            y2 = t11;
            y6 = ((t02 - t00) + 2.f*(t12 - t10) + (t22 - t20)) * 0.125f;
            y10= ((t20 - t00) + 2.f*(t21 - t01) + (t22 - t02)) * 0.125f;
          }
          float u0 = b2r0, u1 = b2r1, u2 = b2r2, u3 = b2r3;
          for (int o = 0; o < 64; ++o) { // weights: wave-uniform scalar loads (K$)
            const float* wr = fc1_w + o*12;
            float t = fc1_b[o];
            t = fmaf(y0, wr[0], t);  t = fmaf(y1, wr[1], t);
            t = fmaf(y2, wr[2], t);  t = fmaf(y3, wr[3], t);
            t = fmaf(y4, wr[4], t);  t = fmaf(y5, wr[5], t);
            t = fmaf(y6, wr[6], t);  t = fmaf(y7, wr[7], t);
            t = fmaf(y8, wr[8], t);  t = fmaf(y9, wr[9], t);
            t = fmaf(y10, wr[10], t); t = fmaf(y11, wr[11], t);
            t = fmaxf(t, 0.f);
            u0 = fmaf(t, fc2_w[o],     u0);
            u1 = fmaf(t, fc2_w[64+o],  u1);
            u2 = fmaf(t, fc2_w[128+o], u2);
            u3 = fmaf(t, fc2_w[192+o], u3);
          }
          x0p[h0] = y0 + u0;             // pre-mask/clip (postmask pool input)
          x1p[p]  = y1 + u1;
          x2p[p]  = y2 + u2;
          x3p[p]  = y3 + u3;
        }
      }
    }
    __syncthreads();                     // (2) staging ready -> C reads
    if (tid < 38) avb[s&1][tid] = 0ull;  // consumed buffer cleared for step s+2
    // --- C: postmask (only where premask), masks+clips, counts ---
    unsigned pq = 0;
    float midv[5];
#pragma unroll
    for (int j = 0; j < 5; ++j) midv[j] = 0.f;
    if (pm) {
      float dm[7];
#pragma unroll
      for (int jc = 0; jc < 7; ++jc) {
        dm[jc] = 0.f;
        if (jc < nval + 2) {
          const int a = pb1 - 1 + jc;
          float u = x0p[a-RS], m = x0p[a], d = x0p[a+RS];
          dm[jc] = fmaxf(fmaxf(u, m), d);
          if (jc >= 1 && jc <= 5) midv[jc-1] = m;   // own x_new ch0 values
        }
      }
#pragma unroll
      for (int j = 0; j < 5; ++j)
        if (fmaxf(fmaxf(dm[j], dm[j+1]), dm[j+2]) > 0.1f) pq |= (1u << j);
    }
    int packed = 0, n1c = 0;             // packed = nz | az<<16 ; n1c = #(v0 == 1.0)
    float v0s[5];
#pragma unroll
    for (int j = 0; j < 5; ++j) {
      v0s[j] = 0.f;
      if (j < nval) {
        bool alive = ((pm >> j) & 1u) && ((pq >> j) & 1u);
        float v0 = 0.f, v1 = 0.f, v2 = 0.f, v3 = 0.f;
        if (alive) {                     // alive ⊆ pm ⊆ am -> staging fresh
          v0 = fminf(fmaxf(midv[j],      0.f),  1.f);
          v1 = fminf(fmaxf(x1p[p0+j], -10.f), 10.f);
          v2 = fminf(fmaxf(x2p[p0+j], -10.f), 10.f);
          v3 = fminf(fmaxf(x3p[p0+j], -10.f), 10.f);
        }
        cb1[pb1+j] = v1; cb2[pb1+j] = v2; v3k[j] = v3;
        v0s[j] = v0;
        int zer = (v0 == 0.f) ? 1 : 0;
        int azf = (zer && v1 == 0.f && v2 == 0.f && v3 == 0.f) ? 1 : 0;
        packed += zer + (azf << 16);
        n1c += (v0 == 1.0f) ? 1 : 0;
      }
    }
#pragma unroll
    for (int off = 32; off; off >>= 1) {
      packed += __shfl_down(packed, off);
      n1c    += __shfl_down(n1c, off);
    }
    if (lane == 0) { inzaz[wid] = packed; ion[wid] = n1c; }
    __syncthreads();                     // (3) counts ready; x3p consumed -> hist usable
    const int t01 = inzaz[0]+inzaz[1]+inzaz[2]+inzaz[3];
    const int nz = t01 & 0xffff, az = t01 >> 16;
    const int n1 = ion[0]+ion[1]+ion[2]+ion[3];
    const int ni = NPIX - nz - n1;       // interior values in (0,1)
    const int cl = icl[s&1][0]+icl[s&1][1]+icl[s&1][2]+icl[s&1][3];
    const int k  = (cl < NPIX) ? cl : (NPIX-1);
    float kth = 0.f;
    // sorted order: zeros | interior (uint order == float order on [0,1)) | ones
    if (k >= nz) {
      if (k - nz >= ni) {
        kth = 1.0f;                      // rank falls in the 1.0 tie block (exact)
      } else {                           // interior rank -> 3-pass radix select
        for (int idx = tid; idx < 1088; idx += NT) hist[idx] = 0;  // x3p garbage -> zero
        __syncthreads();
        const int k2 = k - nz;
#pragma unroll
        for (int j = 0; j < 5; ++j) {
          unsigned u = __float_as_uint(v0s[j]);
          if (j < nval && u != 0u && u != ONEB) atomicAdd(&hist[HIDX(u >> 20)], 1);
        }
        __syncthreads();
        SCAN_PASS(k2);
        __syncthreads();
        const int bin1 = sel_bin; const int kr2 = sel_rem;
#pragma unroll
        for (int j = 0; j < 5; ++j) {
          unsigned u = __float_as_uint(v0s[j]);
          if (j < nval && u != 0u && (u >> 20) == (unsigned)bin1)
            atomicAdd(&hist[HIDX((u >> 10) & 1023u)], 1);
        }
        __syncthreads();
        SCAN_PASS(kr2);
        __syncthreads();
        const int bin2 = sel_bin; const int kr3 = sel_rem;
        const unsigned pref2 = (((unsigned)bin1) << 10) | (unsigned)bin2;
#pragma unroll
        for (int j = 0; j < 5; ++j) {
          unsigned u = __float_as_uint(v0s[j]);
          if (j < nval && u != 0u && (u >> 10) == pref2)
            atomicAdd(&hist[HIDX(u & 1023u)], 1);
        }
        __syncthreads();
        SCAN_PASS(kr3);
        __syncthreads();
        kth = __uint_as_float((((unsigned)bin1) << 20) | (((unsigned)bin2) << 10) | (unsigned)sel_bin);
      }
    }
    // --- writeback + alive bits + next step's living count ---
    unsigned long long avm = 0ull;
    int cnt = 0;
#pragma unroll
    for (int j = 0; j < 5; ++j) {
      if (j < nval) {
        float w0 = (v0s[j] > kth) ? v0s[j] : 0.f;
        c0b[pb1+j] = w0;
        cnt += (w0 > 0.8f) ? 1 : 0;
        if (w0 > 0.1f) avm |= (1ull << j);
      }
    }
    if (avm) atomicOr(&avb[(s+1)&1][trow+2], avm << (c0+2));
#pragma unroll
    for (int off = 32; off; off >>= 1) cnt += __shfl_down(cnt, off);
    if (lane == 0) icl[(s+1)&1][wid] = cnt;
    if (az == NPIX) break;               // all-zero state is an exact fixed point
  }

  // ---------------- epilogue ----------------
  const size_t CELL_N = (size_t)4*NPIX*NB;
  const size_t FOOD_N = (size_t)NPIX*NB;
  float tp = 0.f; int lcv = 0;
#pragma unroll
  for (int j = 0; j < 5; ++j) {
    if (j < nval) {
      const int p = p0 + j;
      float c0v = c0b[pb1+j], c1 = cb1[pb1+j], c2 = cb2[pb1+j]; // self-written
      size_t go = (size_t)b*4*NPIX + p;
      out[go]          = c0v;
      out[go +   NPIX] = c1;
      out[go + 2*NPIX] = c2;
      out[go + 3*NPIX] = v3k[j];
      out[CELL_N + (size_t)b*NPIX + p] = food_in[(size_t)b*NPIX + p];
      tp += c0v;
      lcv += (c0v > 0.1f) ? 1 : 0;
    }
  }
#pragma unroll
  for (int off = 32; off; off >>= 1) { tp += __shfl_down(tp, off); lcv += __shfl_down(lcv, off); }
  if (lane == 0) { fsum[wid] = tp; lcnt[wid] = lcv; }
  __syncthreads();
  if (tid == 0) {
    out[CELL_N + FOOD_N + b]      = fsum[0]+fsum[1]+fsum[2]+fsum[3];
    out[CELL_N + FOOD_N + NB + b] = (float)(lcnt[0]+lcnt[1]+lcnt[2]+lcnt[3]);
  }
}

extern "C" void kernel_launch(void* const* d_in, const int* in_sizes, int n_in,
                              void* d_out, int out_size, void* d_ws, size_t ws_size,
                              hipStream_t stream) {
  const float* cell  = (const float*)d_in[0];
  const float* food  = (const float*)d_in[1];
  const float* fc1w  = (const float*)d_in[2];
  const float* fc1b  = (const float*)d_in[3];
  const float* fc2w  = (const float*)d_in[4];
  const float* fc2b  = (const float*)d_in[5];
  const float* sk    = (const float*)d_in[6];
  const int*   steps = (const int*)d_in[7];
  float* out = (float*)d_out;
  ca_kernel<<<NB, NT, 0, stream>>>(cell, food, fc1w, fc1b, fc2w, fc2b, sk, steps, out);
}

// Round 8
// 226.657 us; speedup vs baseline: 1.0183x; 1.0183x over previous
//
#include <hip/hip_runtime.h>
#include <stdint.h>

#define GD    34
#define RS    39          // row stride; 39%32=7 -> sparse lane aliasing only
#define CBN   (36*RS)     // 1404 words, 1-halo 36x39 buffers
#define NPIX  1156
#define NT    256
#define NB    1024
#define TPR   7           // 5-pixel strips per row (7*5=35 >= 34)
#define TUSED 238         // 34 rows * 7 strips
#define FS    57          // food-halo row stride (init-only, aliases c0b/cb1/cb2)
#define ONEB  0x3f800000u // bits of 1.0f

// pool layout (float offsets)
#define O_C0B 0           // ch0, 1-halo
#define O_CB1 1404        // ch1, 1-halo
#define O_CB2 2808        // ch2, 1-halo
#define O_X0  4212        // x_new ch0 pre-mask/clip, 1-halo
#define O_HIST 5616       // radix histogram, 1088 ints (17-stride mapped, self-clearing)
#define POOLN 6704        // ~26.8 KB -> 4 blocks/CU

// bin -> conflict-free LDS index: groups of 16 bins at stride 17.
// lane L's bins live at 17L..17L+15 -> banks (17L+j)%32 distinct across 32 lanes.
#define HIDX(bb) ((bb) + ((bb) >> 4))

// wave0 scans the 1024-bin histogram, finds the bin containing rank KK,
// writes sel_bin/sel_rem, zeroes the histogram behind itself (self-clearing).
#define SCAN_PASS(KK) do {                                                         \
    if (wid == 0) {                                                                \
      const int hb = 17 * lane;                                                    \
      int c16[16]; int csum = 0;                                                   \
      _Pragma("unroll")                                                            \
      for (int j = 0; j < 16; ++j) { c16[j] = hist[hb+j]; hist[hb+j] = 0; csum += c16[j]; } \
      int inc2 = csum;                                                             \
      _Pragma("unroll")                                                            \
      for (int off2 = 1; off2 < 64; off2 <<= 1) { int vv = __shfl_up(inc2, off2); if (lane >= off2) inc2 += vv; } \
      const int excl = inc2 - csum;                                                \
      if ((KK) >= excl && (KK) < inc2) {                                           \
        int rem = (KK) - excl; int cum = 0;                                        \
        _Pragma("unroll")                                                          \
        for (int j = 0; j < 16; ++j) {                                             \
          if (rem >= cum && rem < cum + c16[j]) { sel_bin = (lane << 4) + j; sel_rem = rem - cum; } \
          cum += c16[j];                                                           \
        }                                                                          \
      }                                                                            \
    }                                                                              \
  } while (0)

__global__ __launch_bounds__(NT) __attribute__((amdgpu_waves_per_eu(4, 4)))
void ca_kernel(const float* __restrict__ cell_in,   // [B,4,34,34]
               const float* __restrict__ food_in,   // [B,34,34]
               const float* __restrict__ fc1_w,     // [64,12] (wave-uniform scalar reads)
               const float* __restrict__ fc1_b,     // [64]
               const float* __restrict__ fc2_w,     // [4,64]
               const float* __restrict__ fc2_b,     // [4]
               const float* __restrict__ sk_g,      // [19,19]
               const int*   __restrict__ steps_p,
               float* __restrict__ out)             // [cell | food | tpv | lc]
{
  __shared__ float pool[POOLN];
  __shared__ unsigned long long avb[2][38]; // alive bits: word=row+2, bit=col+2 (halo=0)
  __shared__ int   icl[2][4];
  __shared__ int   inzaz[4];
  __shared__ int   ion[4];
  __shared__ int   sel_bin, sel_rem;
  __shared__ float fsum[4];
  __shared__ int   lcnt[4];

  float* c0b  = pool + O_C0B;
  float* cb1  = pool + O_CB1;
  float* cb2  = pool + O_CB2;
  float* x0p  = pool + O_X0;
  int*   hist = (int*)(pool + O_HIST);  // dedicated; zero at init, SCAN self-clears
  float* foodc = pool;                  // init-only 52x57 food halo (max idx 2958 < 4212)

  const int tid  = threadIdx.x;
  const int b    = blockIdx.x;
  const int lane = tid & 63;
  const int wid  = tid >> 6;
  const int nsteps = steps_p[0];

  const bool tval = (tid < TUSED);
  const int  trow = tval ? (tid / TPR) : 0;
  const int  c0   = tval ? ((tid % TPR) * 5) : 0;
  const int  nval = tval ? ((c0 <= 29) ? 5 : 4) : 0;   // strip 6 covers cols 30..33
  const int  pb1  = (trow+1)*RS + c0 + 1;              // own pixel in 1-halo bufs
  const int  p0   = trow*GD + c0;                      // flat pixel base
  const int  wb   = trow*RS + c0;                      // 3x7 value-window base (rows trow-1..+1)

  // ---------------- init ----------------
  for (int idx = tid; idx < POOLN; idx += NT) pool[idx] = 0.f;  // includes hist := 0
  for (int idx = tid; idx < 76;    idx += NT) ((unsigned long long*)avb)[idx] = 0ull;
  __syncthreads();

  // food into 9-halo conv scratch (aliases c0b/cb1/cb2 region; re-zeroed after conv)
#pragma unroll
  for (int j = 0; j < 5; ++j)
    if (j < nval) foodc[(trow+9)*FS + (c0+j+9)] = food_in[(size_t)b*NPIX + p0 + j];
  __syncthreads();

  // scent: 19x19 gaussian conv, once. Row-register reuse; per-pixel accumulation order
  // identical to naive dr-outer/dc-inner -> bit-exact.
  float scent[5] = {0.f, 0.f, 0.f, 0.f, 0.f};
  for (int dr = 0; dr < 19; ++dr) {
    const float* frow = foodc + (trow+dr)*FS + c0;
    float f[23];
#pragma unroll
    for (int q = 0; q < 23; ++q) f[q] = frow[q];
    const float* krow = sk_g + dr*19;
#pragma unroll
    for (int dc = 0; dc < 19; ++dc) {
      const float kv = krow[dc];
      scent[0] = fmaf(f[dc+0], kv, scent[0]);
      scent[1] = fmaf(f[dc+1], kv, scent[1]);
      scent[2] = fmaf(f[dc+2], kv, scent[2]);
      scent[3] = fmaf(f[dc+3], kv, scent[3]);
      scent[4] = fmaf(f[dc+4], kv, scent[4]);
    }
  }
  __syncthreads();
  for (int idx = tid; idx < O_X0; idx += NT) pool[idx] = 0.f;  // restore c0b/cb1/cb2 zeros
  __syncthreads();

  // load state; publish initial alive bits + living count
  float v3k[5], v1k[5], v2k[5];
  unsigned long long avm0 = 0ull;
  int cnt0 = 0;
#pragma unroll
  for (int j = 0; j < 5; ++j) {
    v3k[j] = 0.f; v1k[j] = 0.f; v2k[j] = 0.f;
    if (j < nval) {
      const float* gi = cell_in + (size_t)b*4*NPIX + p0 + j;
      float v0 = gi[0], v1 = gi[NPIX], v2 = gi[2*NPIX], v3 = gi[3*NPIX];
      c0b[pb1+j] = v0; cb1[pb1+j] = v1; cb2[pb1+j] = v2;
      v3k[j] = v3;
      cnt0 += (v0 > 0.8f) ? 1 : 0;
      if (v0 > 0.1f) avm0 |= (1ull << j);
      x0p[pb1+j] = scent[j];           // scent staging for step-invariant ch3 sobels
    }
  }
  if (avm0) atomicOr(&avb[0][trow+2], avm0 << (c0+2));
#pragma unroll
  for (int off = 32; off; off >>= 1) cnt0 += __shfl_down(cnt0, off);
  if (lane == 0) icl[0][wid] = cnt0;
  __syncthreads();
  float sxs[5], sys[5];
#pragma unroll
  for (int j = 0; j < 5; ++j) {
    const int bb = (j < nval) ? (pb1 + j) : pb1;
    float t00=x0p[bb-RS-1], t01=x0p[bb-RS], t02=x0p[bb-RS+1];
    float t10=x0p[bb-1],                    t12=x0p[bb+1];
    float t20=x0p[bb+RS-1], t21=x0p[bb+RS], t22=x0p[bb+RS+1];
    sxs[j] = ((t02 - t00) + 2.f*(t12 - t10) + (t22 - t20)) * 0.125f;
    sys[j] = ((t20 - t00) + 2.f*(t21 - t01) + (t22 - t02)) * 0.125f;
  }
  // x0p stale entries are safe: C reads only dilate1(pm) positions == am, all MLP-fresh

  const float b2r0 = fc2_b[0], b2r1 = fc2_b[1], b2r2 = fc2_b[2], b2r3 = fc2_b[3];

  // ---------------- steps ----------------
  for (int s = 0; s < nsteps; ++s) {
    __syncthreads();                     // (1) prev writeback + avb visible
    // --- P1 via alive-bitmask: pm = maxpool3(ch0)>0.1 == OR_3x3(av),
    //     am = maxpool5>0.1 == OR_5x5(av) == dilate1(pm). Exact boolean identities.
    const unsigned long long* av = avb[s&1];
    const unsigned long long q0 = av[trow],   q1 = av[trow+1], q2 = av[trow+2],
                             q3 = av[trow+3], q4 = av[trow+4];
    const unsigned long long or3 = q1 | q2 | q3;
    const unsigned long long or5 = or3 | q0 | q4;
    unsigned pm = 0, am = 0;
#pragma unroll
    for (int j = 0; j < 5; ++j) {
      if (j < nval) {
        if ((or3 >> (c0+j+1)) & 7ull)  pm |= (1u << j);   // cols c0+j-1..c0+j+1
        if ((or5 >> (c0+j))   & 31ull) am |= (1u << j);   // cols c0+j-2..c0+j+2
      }
    }
    // --- MLP: value window + per-pixel gated stencils ---
    if (__any(am != 0u)) {
      float r0[7], r1[7], r2[7];         // ch0 rows trow-1..trow+1, cols c0-1..c0+5
#pragma unroll
      for (int q = 0; q < 7; ++q) r0[q] = c0b[wb + q];
#pragma unroll
      for (int q = 0; q < 7; ++q) r1[q] = c0b[wb + RS + q];
#pragma unroll
      for (int q = 0; q < 7; ++q) r2[q] = c0b[wb + 2*RS + q];
#pragma unroll
      for (int j = 0; j < 5; ++j) {
        int acti = (j < nval) ? (int)((am >> j) & 1u) : 0;
        if (__any(acti)) {
          const int bb = pb1 + j;
          const float y0 = r1[j+1];
          const float y4 = ((r0[j+2] - r0[j]) + 2.f*(r1[j+2] - r1[j]) + (r2[j+2] - r2[j])) * 0.125f;
          const float y8 = ((r2[j] - r0[j]) + 2.f*(r2[j+1] - r0[j+1]) + (r2[j+2] - r0[j+2])) * 0.125f;
          float y1, y5, y9, y2, y6, y10;
          {
            const float* cb = cb1;
            float t00=cb[bb-RS-1], t01=cb[bb-RS], t02=cb[bb-RS+1];
            float t10=cb[bb-1],    t11=cb[bb],    t12=cb[bb+1];
            float t20=cb[bb+RS-1], t21=cb[bb+RS], t22=cb[bb+RS+1];
            y1 = t11;
            y5 = ((t02 - t00) + 2.f*(t12 - t10) + (t22 - t20)) * 0.125f;
            y9 = ((t20 - t00) + 2.f*(t21 - t01) + (t22 - t02)) * 0.125f;
          }
          {
            const float* cb = cb2;
            float t00=cb[bb-RS-1], t01=cb[bb-RS], t02=cb[bb-RS+1];
            float t10=cb[bb-1],    t11=cb[bb],    t12=cb[bb+1];
            float t20=cb[bb+RS-1], t21=cb[bb+RS], t22=cb[bb+RS+1];
            y2 = t11;
            y6 = ((t02 - t00) + 2.f*(t12 - t10) + (t22 - t20)) * 0.125f;
            y10= ((t20 - t00) + 2.f*(t21 - t01) + (t22 - t02)) * 0.125f;
          }
          const float y3 = scent[j], y7 = sxs[j], y11 = sys[j];
          float u0 = b2r0, u1 = b2r1, u2 = b2r2, u3 = b2r3;
          for (int o = 0; o < 64; ++o) { // weights: wave-uniform scalar loads (K$)
            const float* wr = fc1_w + o*12;
            float t = fc1_b[o];
            t = fmaf(y0, wr[0], t);  t = fmaf(y1, wr[1], t);
            t = fmaf(y2, wr[2], t);  t = fmaf(y3, wr[3], t);
            t = fmaf(y4, wr[4], t);  t = fmaf(y5, wr[5], t);
            t = fmaf(y6, wr[6], t);  t = fmaf(y7, wr[7], t);
            t = fmaf(y8, wr[8], t);  t = fmaf(y9, wr[9], t);
            t = fmaf(y10, wr[10], t); t = fmaf(y11, wr[11], t);
            t = fmaxf(t, 0.f);
            u0 = fmaf(t, fc2_w[o],     u0);
            u1 = fmaf(t, fc2_w[64+o],  u1);
            u2 = fmaf(t, fc2_w[128+o], u2);
            u3 = fmaf(t, fc2_w[192+o], u3);
          }
          v3k[j] = y3 + u3;              // x_new ch3, pre-clip
          if (j < nval) {
            x0p[bb]  = y0 + u0;          // x_new ch0, pre-mask/clip (postmask pool input)
            v1k[j]   = y1 + u1;          // x_new ch1/ch2 stay in registers
            v2k[j]   = y2 + u2;
          }
        }
      }
    }
    __syncthreads();                     // (2) x0p writes -> C reads
    if (tid < 38) avb[s&1][tid] = 0ull;  // consumed buffer cleared for step s+2
    // --- C: postmask (only where premask), masks+clips, counts ---
    unsigned pq = 0;
    float midv[5];
#pragma unroll
    for (int j = 0; j < 5; ++j) midv[j] = 0.f;
    if (pm) {
      float dm[7];
#pragma unroll
      for (int jc = 0; jc < 7; ++jc) {
        dm[jc] = 0.f;
        if (jc < nval + 2) {
          const int a = pb1 - 1 + jc;
          float u = x0p[a-RS], m = x0p[a], d = x0p[a+RS];
          dm[jc] = fmaxf(fmaxf(u, m), d);
          if (jc >= 1 && jc <= 5) midv[jc-1] = m;   // own x_new ch0 values
        }
      }
#pragma unroll
      for (int j = 0; j < 5; ++j)
        if (fmaxf(fmaxf(dm[j], dm[j+1]), dm[j+2]) > 0.1f) pq |= (1u << j);
    }
    int packed = 0, n1c = 0;             // packed = nz | az<<16 ; n1c = #(v0 == 1.0)
    float v0s[5];
#pragma unroll
    for (int j = 0; j < 5; ++j) {
      v0s[j] = 0.f;
      if (j < nval) {
        bool alive = ((pm >> j) & 1u) && ((pq >> j) & 1u);
        float v0 = 0.f, v1 = 0.f, v2 = 0.f, v3 = 0.f;
        if (alive) {                     // alive ⊆ pm ⊆ am -> all inputs fresh
          v0 = fminf(fmaxf(midv[j],   0.f),  1.f);
          v1 = fminf(fmaxf(v1k[j],  -10.f), 10.f);
          v2 = fminf(fmaxf(v2k[j],  -10.f), 10.f);
          v3 = fminf(fmaxf(v3k[j],  -10.f), 10.f);
        }
        cb1[pb1+j] = v1; cb2[pb1+j] = v2; v3k[j] = v3;
        v0s[j] = v0;
        int zer = (v0 == 0.f) ? 1 : 0;
        int azf = (zer && v1 == 0.f && v2 == 0.f && v3 == 0.f) ? 1 : 0;
        packed += zer + (azf << 16);
        n1c += (v0 == 1.0f) ? 1 : 0;
      }
    }
#pragma unroll
    for (int off = 32; off; off >>= 1) {
      packed += __shfl_down(packed, off);
      n1c    += __shfl_down(n1c, off);
    }
    if (lane == 0) { inzaz[wid] = packed; ion[wid] = n1c; }
    __syncthreads();                     // (3) counts ready; x0p fully consumed
    const int t01 = inzaz[0]+inzaz[1]+inzaz[2]+inzaz[3];
    const int nz = t01 & 0xffff, az = t01 >> 16;
    const int n1 = ion[0]+ion[1]+ion[2]+ion[3];
    const int ni = NPIX - nz - n1;       // interior values in (0,1)
    const int cl = icl[s&1][0]+icl[s&1][1]+icl[s&1][2]+icl[s&1][3];
    const int k  = (cl < NPIX) ? cl : (NPIX-1);
    float kth = 0.f;
    // sorted order: zeros | interior (uint order == float order on [0,1)) | ones
    if (k >= nz) {
      if (k - nz >= ni) {
        kth = 1.0f;                      // rank falls in the 1.0 tie block (exact)
      } else {                           // interior rank -> 3-pass radix select
        const int k2 = k - nz;           // hist is all-zero here (init / self-cleared)
#pragma unroll
        for (int j = 0; j < 5; ++j) {
          unsigned u = __float_as_uint(v0s[j]);
          if (j < nval && u != 0u && u != ONEB) atomicAdd(&hist[HIDX(u >> 20)], 1);
        }
        __syncthreads();
        SCAN_PASS(k2);
        __syncthreads();
        const int bin1 = sel_bin; const int kr2 = sel_rem;
        // interior bins are <=1015 (exp<127), so ones (bin 1016) can never match bin1
#pragma unroll
        for (int j = 0; j < 5; ++j) {
          unsigned u = __float_as_uint(v0s[j]);
          if (j < nval && u != 0u && (u >> 20) == (unsigned)bin1)
            atomicAdd(&hist[HIDX((u >> 10) & 1023u)], 1);
        }
        __syncthreads();
        SCAN_PASS(kr2);
        __syncthreads();
        const int bin2 = sel_bin; const int kr3 = sel_rem;
        const unsigned pref2 = (((unsigned)bin1) << 10) | (unsigned)bin2;
#pragma unroll
        for (int j = 0; j < 5; ++j) {
          unsigned u = __float_as_uint(v0s[j]);
          if (j < nval && u != 0u && (u >> 10) == pref2)
            atomicAdd(&hist[HIDX(u & 1023u)], 1);
        }
        __syncthreads();
        SCAN_PASS(kr3);
        __syncthreads();
        kth = __uint_as_float((((unsigned)bin1) << 20) | (((unsigned)bin2) << 10) | (unsigned)sel_bin);
        // SCAN self-clears hist -> all-zero invariant restored
      }
    }
    // --- writeback + alive bits + next step's living count ---
    unsigned long long avm = 0ull;
    int cnt = 0;
#pragma unroll
    for (int j = 0; j < 5; ++j) {
      if (j < nval) {
        float w0 = (v0s[j] > kth) ? v0s[j] : 0.f;
        c0b[pb1+j] = w0;
        cnt += (w0 > 0.8f) ? 1 : 0;
        if (w0 > 0.1f) avm |= (1ull << j);
      }
    }
    if (avm) atomicOr(&avb[(s+1)&1][trow+2], avm << (c0+2));
#pragma unroll
    for (int off = 32; off; off >>= 1) cnt += __shfl_down(cnt, off);
    if (lane == 0) icl[(s+1)&1][wid] = cnt;
    if (az == NPIX) break;               // all-zero state is an exact fixed point
  }

  // ---------------- epilogue ----------------
  const size_t CELL_N = (size_t)4*NPIX*NB;
  const size_t FOOD_N = (size_t)NPIX*NB;
  float tp = 0.f; int lcv = 0;
#pragma unroll
  for (int j = 0; j < 5; ++j) {
    if (j < nval) {
      const int p = p0 + j;
      float c0v = c0b[pb1+j], c1 = cb1[pb1+j], c2 = cb2[pb1+j]; // self-written
      size_t go = (size_t)b*4*NPIX + p;
      out[go]          = c0v;
      out[go +   NPIX] = c1;
      out[go + 2*NPIX] = c2;
      out[go + 3*NPIX] = v3k[j];
      out[CELL_N + (size_t)b*NPIX + p] = food_in[(size_t)b*NPIX + p];
      tp += c0v;
      lcv += (c0v > 0.1f) ? 1 : 0;
    }
  }
#pragma unroll
  for (int off = 32; off; off >>= 1) { tp += __shfl_down(tp, off); lcv += __shfl_down(lcv, off); }
  if (lane == 0) { fsum[wid] = tp; lcnt[wid] = lcv; }
  __syncthreads();
  if (tid == 0) {
    out[CELL_N + FOOD_N + b]      = fsum[0]+fsum[1]+fsum[2]+fsum[3];
    out[CELL_N + FOOD_N + NB + b] = (float)(lcnt[0]+lcnt[1]+lcnt[2]+lcnt[3]);
  }
}

extern "C" void kernel_launch(void* const* d_in, const int* in_sizes, int n_in,
                              void* d_out, int out_size, void* d_ws, size_t ws_size,
                              hipStream_t stream) {
  const float* cell  = (const float*)d_in[0];
  const float* food  = (const float*)d_in[1];
  const float* fc1w  = (const float*)d_in[2];
  const float* fc1b  = (const float*)d_in[3];
  const float* fc2w  = (const float*)d_in[4];
  const float* fc2b  = (const float*)d_in[5];
  const float* sk    = (const float*)d_in[6];
  const int*   steps = (const int*)d_in[7];
  float* out = (float*)d_out;
  ca_kernel<<<NB, NT, 0, stream>>>(cell, food, fc1w, fc1b, fc2w, fc2b, sk, steps, out);
}